// Round 4
// baseline (138.549 us; speedup 1.0000x reference)
//
#include <hip/hip_runtime.h>

// FilterBank: x (128,22,2000) f32, a,b (9,9) f32 -> y (128,22,9,2000) f32
// y[t] = sum_k bn[k] x[t-k] - sum_{k>=1} an[k] y[t-k], zero init state.
//
// R4: EXACT chunk decomposition via linear-state scan (no warm-up):
//   pass1: per (filter, chunk) run 64-step chunk from zero state, emit final
//          8-dim y-state only (states0, stored in d_out scratch region).
//   passM: M = A^lch (8x8 companion-matrix power) per band, via 8 unit
//          homogeneous responses. 1 block.
//   pass2: per-filter scan: s_init[c] = states0[c-1] + M*s_init[c-1]  (d_ws).
//   pass3: per (filter, chunk) re-run chunk with exact init state, write y.
// Work = 2x2000 steps/filter (< R3's 4176), parallelism 12672 waves
// (49.5/CU vs 12.4). Exact -> absmax should match R1 (0.0078).

#define TT 2000
#define KK 9
#define NB 9
#define CH 16

__device__ __forceinline__ void load_coeffs(const float* a, const float* b,
                                            int band, float* an, float* bn) {
    const float inv = 1.0f / a[band * KK];
    #pragma unroll
    for (int k = 0; k < KK; ++k) {
        an[k] = a[band * KK + k] * inv;
        bn[k] = b[band * KK + k] * inv;
    }
}

// MODE 0: compute chunk from zero state, write final state to st.
// MODE 1: compute chunk from st init state (or zero if st==null), write y.
template<int MODE>
__global__ __launch_bounds__(256) void fb_chunk_kernel(
    const float* __restrict__ x,
    const float* __restrict__ a,
    const float* __restrict__ b,
    float* __restrict__ y,
    float* __restrict__ st,
    int nfil, int lch, int log2nchunk)
{
    const int gid  = blockIdx.x * 256 + threadIdx.x;
    const int w    = gid >> 6;
    const int lane = gid & 63;
    const int c    = w & ((1 << log2nchunk) - 1);   // chunk (pow2 count)
    const int fw   = w >> log2nchunk;
    const int fil  = fw * 64 + lane;
    const int seq  = fil / NB;
    const int band = fil - seq * NB;

    const int t0    = c * lch;                      // mult of 16
    const int t_end = (t0 + lch < TT) ? t0 + lch : TT;
    const int nit   = (t_end - t0) >> 4;

    const float* xrow = x + (size_t)seq * TT;

    float an[KK], bn[KK];
    load_coeffs(a, b, band, an, bn);

    float xh[8], yh[8];
    #pragma unroll
    for (int m = 0; m < 8; ++m) {
        const int t = t0 - 1 - m;
        xh[m] = (t >= 0) ? xrow[t] : 0.f;           // exact x history
        yh[m] = 0.f;
    }
    if (MODE == 1 && st != nullptr) {               // exact y init state
        const float4* sv = (const float4*)(st + ((size_t)c * nfil + fil) * 8);
        float4 s0 = sv[0], s1 = sv[1];
        yh[0]=s0.x; yh[1]=s0.y; yh[2]=s0.z; yh[3]=s0.w;
        yh[4]=s1.x; yh[5]=s1.y; yh[6]=s1.z; yh[7]=s1.w;
    }

    const float4* xv = (const float4*)(xrow + t0);
    float4*       yv = (float4*)(y + (size_t)fil * TT + t0);

    float4 c0 = xv[0], c1 = xv[1], c2 = xv[2], c3 = xv[3];

    for (int it = 0; it < nit; ++it) {
        const int in = (it + 1 < nit) ? it + 1 : it;     // clamped prefetch
        float4 n0 = xv[in*4+0], n1 = xv[in*4+1], n2 = xv[in*4+2], n3 = xv[in*4+3];

        float xc[CH] = { c0.x,c0.y,c0.z,c0.w, c1.x,c1.y,c1.z,c1.w,
                         c2.x,c2.y,c2.z,c2.w, c3.x,c3.y,c3.z,c3.w };
        float yc[CH];

        #pragma unroll
        for (int i = 0; i < CH; ++i) {
            float s = bn[0] * xc[i];
            #pragma unroll
            for (int k = 1; k < KK; ++k) {
                const float xt = (i - k >= 0) ? xc[i - k] : xh[k - i - 1];
                s = fmaf(bn[k], xt, s);
            }
            #pragma unroll
            for (int k = 2; k < KK; ++k) {
                const float yt = (i - k >= 0) ? yc[i - k] : yh[k - i - 1];
                s = fmaf(-an[k], yt, s);
            }
            const float y1 = (i >= 1) ? yc[i - 1] : yh[0];
            yc[i] = fmaf(-an[1], y1, s);   // cross-step critical path = 1 FMA
        }

        if (MODE == 1) {
            yv[it*4+0] = make_float4(yc[0],  yc[1],  yc[2],  yc[3]);
            yv[it*4+1] = make_float4(yc[4],  yc[5],  yc[6],  yc[7]);
            yv[it*4+2] = make_float4(yc[8],  yc[9],  yc[10], yc[11]);
            yv[it*4+3] = make_float4(yc[12], yc[13], yc[14], yc[15]);
        }

        #pragma unroll
        for (int m = 0; m < 8; ++m) {
            xh[m] = xc[CH - 1 - m];
            yh[m] = yc[CH - 1 - m];
        }
        c0 = n0; c1 = n1; c2 = n2; c3 = n3;
    }

    if (MODE == 0) {                       // final state: yh[m] = y[t_end-1-m]
        float4* sv = (float4*)(st + ((size_t)c * nfil + fil) * 8);
        sv[0] = make_float4(yh[0], yh[1], yh[2], yh[3]);
        sv[1] = make_float4(yh[4], yh[5], yh[6], yh[7]);
    }
}

// M[band] = A^lch : column j = homogeneous response after lch steps from e_j.
__global__ void fb_mat_kernel(const float* __restrict__ a,
                              float* __restrict__ M, int lch)
{
    const int tid = threadIdx.x;
    if (tid >= NB * 8) return;
    const int band = tid >> 3, j = tid & 7;

    float an[KK];
    const float inv = 1.0f / a[band * KK];
    #pragma unroll
    for (int k = 0; k < KK; ++k) an[k] = a[band * KK + k] * inv;

    float yh[8] = {0.f,0.f,0.f,0.f,0.f,0.f,0.f,0.f};
    yh[j] = 1.0f;
    for (int t = 0; t < lch; ++t) {
        float s = 0.f;
        #pragma unroll
        for (int k = 1; k < KK; ++k) s = fmaf(-an[k], yh[k - 1], s);
        #pragma unroll
        for (int m = 7; m >= 1; --m) yh[m] = yh[m - 1];
        yh[0] = s;
    }
    #pragma unroll
    for (int m = 0; m < 8; ++m) M[band * 64 + m * 8 + j] = yh[m];
}

// Per-filter scan: sinit[0]=0; sinit[c] = states0[c-1] + M * sinit[c-1].
__global__ __launch_bounds__(256) void fb_scan_kernel(
    const float* __restrict__ states0,
    const float* __restrict__ Mg,
    float* __restrict__ sinit,
    int nfil, int nchunk)
{
    __shared__ float Ms[NB * 64];
    for (int i = threadIdx.x; i < NB * 64; i += 256) Ms[i] = Mg[i];
    __syncthreads();

    const int fil = blockIdx.x * 256 + threadIdx.x;
    const int band = fil % NB;
    const float* Mb = &Ms[band * 64];

    float s[8] = {0.f,0.f,0.f,0.f,0.f,0.f,0.f,0.f};
    // prefetch chunk-0 end state
    float4 e0 = ((const float4*)(states0 + (size_t)fil * 8))[0];
    float4 e1 = ((const float4*)(states0 + (size_t)fil * 8))[1];

    for (int c = 0; c < nchunk; ++c) {
        float4* sv = (float4*)(sinit + ((size_t)c * nfil + fil) * 8);
        sv[0] = make_float4(s[0], s[1], s[2], s[3]);
        sv[1] = make_float4(s[4], s[5], s[6], s[7]);
        if (c == nchunk - 1) break;

        const float e[8] = {e0.x,e0.y,e0.z,e0.w, e1.x,e1.y,e1.z,e1.w};
        // prefetch next end state while matvec runs
        const int cn = (c + 1 < nchunk - 1) ? c + 1 : c;
        e0 = ((const float4*)(states0 + ((size_t)cn * nfil + fil) * 8))[0];
        e1 = ((const float4*)(states0 + ((size_t)cn * nfil + fil) * 8))[1];

        float ns[8];
        #pragma unroll
        for (int m = 0; m < 8; ++m) {
            float acc = e[m];
            #pragma unroll
            for (int j = 0; j < 8; ++j) acc = fmaf(Mb[m * 8 + j], s[j], acc);
            ns[m] = acc;
        }
        #pragma unroll
        for (int m = 0; m < 8; ++m) s[m] = ns[m];
    }
}

extern "C" void kernel_launch(void* const* d_in, const int* in_sizes, int n_in,
                              void* d_out, int out_size, void* d_ws, size_t ws_size,
                              hipStream_t stream) {
    const float* x = (const float*)d_in[0];
    const float* a = (const float*)d_in[1];
    const float* b = (const float*)d_in[2];
    float*       y = (float*)d_out;

    const int nseq = in_sizes[0] / TT;      // 2816
    const int nfil = nseq * NB;             // 25344 (mult of 256)

    // pick largest pow2 nchunk whose sinit (+ M buffer) fits in d_ws
    int log2n = 5;
    while (log2n > 0) {
        const size_t need = (size_t)(576 + ((size_t)1 << log2n) * (size_t)nfil * 8) * 4;
        if (need <= ws_size) break;
        --log2n;
    }
    const int nchunk = 1 << log2n;
    const int lch = (((TT + nchunk - 1) / nchunk) + 15) / 16 * 16;  // 64/128/256/512/1008/2000

    const size_t min_need = (size_t)(576 + (size_t)nfil * 8) * 4;
    if (ws_size < min_need) {
        // no usable scratch: single exact kernel, zero init (R1 path)
        fb_chunk_kernel<1><<<nfil / 256, 256, 0, stream>>>(
            x, a, b, y, nullptr, nfil, TT, 0);
        return;
    }

    float* Mbuf   = (float*)d_ws;                    // 576 floats
    float* sinit  = (float*)d_ws + 576;              // nchunk*nfil*8 floats
    float* states = (float*)d_out;                   // scratch; dead before pass3

    const int grid = nfil * nchunk / 256;            // 3168 at nchunk=32

    fb_chunk_kernel<0><<<grid, 256, 0, stream>>>(x, a, b, nullptr, states,
                                                 nfil, lch, log2n);
    fb_mat_kernel<<<1, 128, 0, stream>>>(a, Mbuf, lch);
    fb_scan_kernel<<<nfil / 256, 256, 0, stream>>>(states, Mbuf, sinit,
                                                   nfil, nchunk);
    fb_chunk_kernel<1><<<grid, 256, 0, stream>>>(x, a, b, y, sinit,
                                                 nfil, lch, log2n);
}

// Round 5
// 124.019 us; speedup vs baseline: 1.1172x; 1.1172x over previous
//
#include <hip/hip_runtime.h>

// FilterBank: x (128,22,2000) f32, a,b (9,9) f32 -> y (128,22,9,2000) f32
// y[t] = sum_k bn[k] x[t-k] - sum_{k>=1} an[k] y[t-k], zero init state.
//
// R5: exact chunk-scan structure of R4 (pass1 states -> M=A^64 -> scan ->
// pass3 rewrite), with both heavy passes rebuilt to fix vector-memory
// REQUEST cost (R1-R4 were request-bound: 64 scattered lines per store
// instr, 9x-duplicated x loads):
//  - block = 576 thr = 9 waves = (64 seqs x 9 bands); wave == band ->
//    coefficients are wave-uniform scalar loads (readfirstlane).
//  - x tile (64 seqs x [t0-8, t0+64)) staged once per block in LDS,
//    coalesced; 9x dedup of x reads.
//  - pass3 stores transposed through LDS: 4 lanes per 64B line -> full-line
//    writes (16 req/instr vs 64).
//  - LDS strides: XP=76 floats (x rows spread over all 8 16B bank-groups for
//    b128), YQ=20 floats (5r mod 8 bijective) -> conflict-free.

#define TT 2000
#define KK 9
#define NB 9
#define LCH 64
#define NCHUNK 32
#define NSEQG 64
#define XP 76          // x_lds row stride (floats): 8 hist + 64 data + pad
#define YQ 20          // y_lds row stride (floats): 16 data + pad
#define BLK 576        // 9 waves

// ---- 16-step IIR core: xc[16] in, yc[16] out, xh/yh histories updated ----
__device__ __forceinline__ void step16(const float* an, const float* bn,
                                       const float* xc, float* yc,
                                       float* xh, float* yh)
{
#pragma unroll
    for (int i = 0; i < 16; ++i) {
        float s = bn[0] * xc[i];
#pragma unroll
        for (int k = 1; k < KK; ++k) {
            const float xt = (i - k >= 0) ? xc[i - k] : xh[k - i - 1];
            s = fmaf(bn[k], xt, s);
        }
#pragma unroll
        for (int k = 2; k < KK; ++k) {
            const float yt = (i - k >= 0) ? yc[i - k] : yh[k - i - 1];
            s = fmaf(-an[k], yt, s);
        }
        const float y1 = (i >= 1) ? yc[i - 1] : yh[0];
        yc[i] = fmaf(-an[1], y1, s);   // cross-step critical path = 1 FMA
    }
#pragma unroll
    for (int m = 0; m < 8; ++m) { xh[m] = xc[15 - m]; yh[m] = yc[15 - m]; }
}

// cooperative x tile load: rows [seq0, seq0+64), floats [t0-8, t0+64)
// 64 rows x 18 float4 = 1152 float4s; 576 threads x 2. All float4s are
// either fully in [0,TT) or fully outside (t0-8 and TT are mult of 4).
__device__ __forceinline__ void load_xtile(const float* __restrict__ x,
                                           float* xs, int seq0, int t0, int tid)
{
#pragma unroll
    for (int u = 0; u < 2; ++u) {
        const int i4 = tid + u * BLK;
        const int r2 = i4 / 18;
        const int j4 = i4 - r2 * 18;
        const int gt = t0 - 8 + j4 * 4;
        float4 v = make_float4(0.f, 0.f, 0.f, 0.f);
        if (gt >= 0 && gt <= TT - 4)
            v = *(const float4*)(x + (size_t)(seq0 + r2) * TT + gt);
        *(float4*)(&xs[r2 * XP + j4 * 4]) = v;
    }
}

// ---- pass1: chunk from zero y-state (exact x history), emit end state ----
__global__ __launch_bounds__(BLK) void fb_pass1(
    const float* __restrict__ x, const float* __restrict__ a,
    const float* __restrict__ b, float* __restrict__ st, int nfil)
{
    __shared__ float xs[NSEQG * XP];                 // 19456 B
    const int tid  = threadIdx.x;
    const int c    = blockIdx.x & (NCHUNK - 1);
    const int g    = blockIdx.x >> 5;
    const int seq0 = g * NSEQG;
    const int t0   = c * LCH;
    const int nit  = (c == NCHUNK - 1) ? ((TT - t0 + 15) >> 4) : (LCH >> 4);

    load_xtile(x, xs, seq0, t0, tid);

    const int w = __builtin_amdgcn_readfirstlane(tid >> 6);   // band, SGPR
    const int r = tid & 63;

    float an[KK], bn[KK];
    {
        const float inv = 1.0f / a[w * KK];
#pragma unroll
        for (int k = 0; k < KK; ++k) {
            an[k] = a[w * KK + k] * inv;
            bn[k] = b[w * KK + k] * inv;
        }
    }

    __syncthreads();

    float xh[8], yh[8] = {0.f,0.f,0.f,0.f,0.f,0.f,0.f,0.f};
    {
        float4 h0 = *(const float4*)(&xs[r * XP]);       // x[t0-8..t0-5]
        float4 h1 = *(const float4*)(&xs[r * XP + 4]);   // x[t0-4..t0-1]
        xh[0]=h1.w; xh[1]=h1.z; xh[2]=h1.y; xh[3]=h1.x;
        xh[4]=h0.w; xh[5]=h0.z; xh[6]=h0.y; xh[7]=h0.x;
    }

    for (int it = 0; it < nit; ++it) {
        float xc[16], yc[16];
        const float4* xb = (const float4*)(&xs[r * XP + 8 + it * 16]);
        float4 v0 = xb[0], v1 = xb[1], v2 = xb[2], v3 = xb[3];
        xc[0]=v0.x; xc[1]=v0.y; xc[2]=v0.z; xc[3]=v0.w;
        xc[4]=v1.x; xc[5]=v1.y; xc[6]=v1.z; xc[7]=v1.w;
        xc[8]=v2.x; xc[9]=v2.y; xc[10]=v2.z; xc[11]=v2.w;
        xc[12]=v3.x; xc[13]=v3.y; xc[14]=v3.z; xc[15]=v3.w;
        step16(an, bn, xc, yc, xh, yh);
    }

    const int fil = (seq0 + r) * NB + w;
    float4* sv = (float4*)(st + ((size_t)c * nfil + fil) * 8);
    sv[0] = make_float4(yh[0], yh[1], yh[2], yh[3]);
    sv[1] = make_float4(yh[4], yh[5], yh[6], yh[7]);
}

// ---- M[band] = A^LCH: column j = homogeneous response from e_j ----
__global__ void fb_mat_kernel(const float* __restrict__ a,
                              float* __restrict__ M, int lch)
{
    const int tid = threadIdx.x;
    if (tid >= NB * 8) return;
    const int band = tid >> 3, j = tid & 7;

    float an[KK];
    const float inv = 1.0f / a[band * KK];
#pragma unroll
    for (int k = 0; k < KK; ++k) an[k] = a[band * KK + k] * inv;

    float yh[8] = {0.f,0.f,0.f,0.f,0.f,0.f,0.f,0.f};
    yh[j] = 1.0f;
    for (int t = 0; t < lch; ++t) {
        float s = 0.f;
#pragma unroll
        for (int k = 1; k < KK; ++k) s = fmaf(-an[k], yh[k - 1], s);
#pragma unroll
        for (int m = 7; m >= 1; --m) yh[m] = yh[m - 1];
        yh[0] = s;
    }
#pragma unroll
    for (int m = 0; m < 8; ++m) M[band * 64 + m * 8 + j] = yh[m];
}

// ---- scan: sinit[0]=0; sinit[c] = states0[c-1] + M*sinit[c-1] ----
__global__ __launch_bounds__(256) void fb_scan_kernel(
    const float* __restrict__ states0,
    const float* __restrict__ Mg,
    float* __restrict__ sinit,
    int nfil, int nchunk)
{
    __shared__ float Ms[NB * 64];
    for (int i = threadIdx.x; i < NB * 64; i += 256) Ms[i] = Mg[i];
    __syncthreads();

    const int fil  = blockIdx.x * 256 + threadIdx.x;
    const int band = fil % NB;
    const float* Mb = &Ms[band * 64];

    float s[8] = {0.f,0.f,0.f,0.f,0.f,0.f,0.f,0.f};
    float4 e0 = ((const float4*)(states0 + (size_t)fil * 8))[0];
    float4 e1 = ((const float4*)(states0 + (size_t)fil * 8))[1];

    for (int c = 0; c < nchunk; ++c) {
        float4* sv = (float4*)(sinit + ((size_t)c * nfil + fil) * 8);
        sv[0] = make_float4(s[0], s[1], s[2], s[3]);
        sv[1] = make_float4(s[4], s[5], s[6], s[7]);
        if (c == nchunk - 1) break;

        const float e[8] = {e0.x,e0.y,e0.z,e0.w, e1.x,e1.y,e1.z,e1.w};
        const int cn = (c + 1 < nchunk - 1) ? c + 1 : c;
        e0 = ((const float4*)(states0 + ((size_t)cn * nfil + fil) * 8))[0];
        e1 = ((const float4*)(states0 + ((size_t)cn * nfil + fil) * 8))[1];

        float ns[8];
#pragma unroll
        for (int m = 0; m < 8; ++m) {
            float acc = e[m];
#pragma unroll
            for (int j = 0; j < 8; ++j) acc = fmaf(Mb[m * 8 + j], s[j], acc);
            ns[m] = acc;
        }
#pragma unroll
        for (int m = 0; m < 8; ++m) s[m] = ns[m];
    }
}

// ---- pass3: chunk from exact init state, write y via LDS transpose ----
__global__ __launch_bounds__(BLK) void fb_pass3(
    const float* __restrict__ x, const float* __restrict__ a,
    const float* __restrict__ b, const float* __restrict__ sinit,
    float* __restrict__ y, int nfil)
{
    __shared__ float xs[NSEQG * XP];                 // 19456 B
    __shared__ float ys[BLK * YQ];                   // 46080 B (65536 total)
    const int tid  = threadIdx.x;
    const int c    = blockIdx.x & (NCHUNK - 1);
    const int g    = blockIdx.x >> 5;
    const int seq0 = g * NSEQG;
    const int t0   = c * LCH;
    const int nit  = (c == NCHUNK - 1) ? ((TT - t0 + 15) >> 4) : (LCH >> 4);

    load_xtile(x, xs, seq0, t0, tid);

    const int w = __builtin_amdgcn_readfirstlane(tid >> 6);   // band, SGPR
    const int r = tid & 63;
    const int fil = (seq0 + r) * NB + w;

    float an[KK], bn[KK];
    {
        const float inv = 1.0f / a[w * KK];
#pragma unroll
        for (int k = 0; k < KK; ++k) {
            an[k] = a[w * KK + k] * inv;
            bn[k] = b[w * KK + k] * inv;
        }
    }

    float xh[8], yh[8];
    {
        const float4* sv = (const float4*)(sinit + ((size_t)c * nfil + fil) * 8);
        float4 s0 = sv[0], s1 = sv[1];
        yh[0]=s0.x; yh[1]=s0.y; yh[2]=s0.z; yh[3]=s0.w;
        yh[4]=s1.x; yh[5]=s1.y; yh[6]=s1.z; yh[7]=s1.w;
    }

    __syncthreads();

    {
        float4 h0 = *(const float4*)(&xs[r * XP]);
        float4 h1 = *(const float4*)(&xs[r * XP + 4]);
        xh[0]=h1.w; xh[1]=h1.z; xh[2]=h1.y; xh[3]=h1.x;
        xh[4]=h0.w; xh[5]=h0.z; xh[6]=h0.y; xh[7]=h0.x;
    }

    const int q  = r >> 2;       // 0..15
    const int cc = r & 3;        // 16B chunk within 64B line

    for (int it = 0; it < nit; ++it) {
        float xc[16], yc[16];
        const float4* xb = (const float4*)(&xs[r * XP + 8 + it * 16]);
        float4 v0 = xb[0], v1 = xb[1], v2 = xb[2], v3 = xb[3];
        xc[0]=v0.x; xc[1]=v0.y; xc[2]=v0.z; xc[3]=v0.w;
        xc[4]=v1.x; xc[5]=v1.y; xc[6]=v1.z; xc[7]=v1.w;
        xc[8]=v2.x; xc[9]=v2.y; xc[10]=v2.z; xc[11]=v2.w;
        xc[12]=v3.x; xc[13]=v3.y; xc[14]=v3.z; xc[15]=v3.w;
        step16(an, bn, xc, yc, xh, yh);

        // stage own row (wave-private region; same-wave DS ops are in-order)
        float* yl = &ys[(w * 64 + r) * YQ];
        ((float4*)yl)[0] = make_float4(yc[0],  yc[1],  yc[2],  yc[3]);
        ((float4*)yl)[1] = make_float4(yc[4],  yc[5],  yc[6],  yc[7]);
        ((float4*)yl)[2] = make_float4(yc[8],  yc[9],  yc[10], yc[11]);
        ((float4*)yl)[3] = make_float4(yc[12], yc[13], yc[14], yc[15]);
        asm volatile("s_waitcnt lgkmcnt(0)" ::: "memory");

        // transposed store: 4 lanes per fil -> full 64B lines
#pragma unroll
        for (int s = 0; s < 4; ++s) {
            const int row = s * 16 + q;                     // fil-local in wave
            float4 v = *(const float4*)(&ys[(w * 64 + row) * YQ + cc * 4]);
            float* dst = y + ((size_t)(seq0 + row) * NB + w) * TT
                           + t0 + it * 16 + cc * 4;
            *(float4*)dst = v;
        }
    }
}

// ---- fallback: exact thread-per-filter, full length (R1 design) ----
__global__ __launch_bounds__(64) void fb_fallback(
    const float* __restrict__ x, const float* __restrict__ a,
    const float* __restrict__ b, float* __restrict__ y, int nfil)
{
    const int tid = blockIdx.x * 64 + threadIdx.x;
    if (tid >= nfil) return;
    const int seq  = tid / NB;
    const int band = tid - seq * NB;

    const float* xp = x + (size_t)seq * TT;
    float*       yp = y + (size_t)tid * TT;

    float an[KK], bn[KK];
    const float inv = 1.0f / a[band * KK];
#pragma unroll
    for (int k = 0; k < KK; ++k) {
        an[k] = a[band * KK + k] * inv;
        bn[k] = b[band * KK + k] * inv;
    }

    float xh[8] = {0.f,0.f,0.f,0.f,0.f,0.f,0.f,0.f};
    float yh[8] = {0.f,0.f,0.f,0.f,0.f,0.f,0.f,0.f};

    for (int t0 = 0; t0 < TT; t0 += 16) {
        float xc[16], yc[16];
        const float4* xv = (const float4*)(xp + t0);
        float4 v0 = xv[0], v1 = xv[1], v2 = xv[2], v3 = xv[3];
        xc[0]=v0.x; xc[1]=v0.y; xc[2]=v0.z; xc[3]=v0.w;
        xc[4]=v1.x; xc[5]=v1.y; xc[6]=v1.z; xc[7]=v1.w;
        xc[8]=v2.x; xc[9]=v2.y; xc[10]=v2.z; xc[11]=v2.w;
        xc[12]=v3.x; xc[13]=v3.y; xc[14]=v3.z; xc[15]=v3.w;
        step16(an, bn, xc, yc, xh, yh);
        float4* yv = (float4*)(yp + t0);
        yv[0] = make_float4(yc[0],  yc[1],  yc[2],  yc[3]);
        yv[1] = make_float4(yc[4],  yc[5],  yc[6],  yc[7]);
        yv[2] = make_float4(yc[8],  yc[9],  yc[10], yc[11]);
        yv[3] = make_float4(yc[12], yc[13], yc[14], yc[15]);
    }
}

extern "C" void kernel_launch(void* const* d_in, const int* in_sizes, int n_in,
                              void* d_out, int out_size, void* d_ws, size_t ws_size,
                              hipStream_t stream) {
    const float* x = (const float*)d_in[0];
    const float* a = (const float*)d_in[1];
    const float* b = (const float*)d_in[2];
    float*       y = (float*)d_out;

    const int nseq = in_sizes[0] / TT;      // 2816
    const int nfil = nseq * NB;             // 25344

    const size_t need = (size_t)(576 + (size_t)NCHUNK * nfil * 8) * 4;  // ~26 MB
    if ((nseq % NSEQG) != 0 || (nfil % 256) != 0 || need > ws_size) {
        fb_fallback<<<(nfil + 63) / 64, 64, 0, stream>>>(x, a, b, y, nfil);
        return;
    }

    float* Mbuf   = (float*)d_ws;                 // 576 floats
    float* sinit  = (float*)d_ws + 576;           // NCHUNK*nfil*8 floats
    float* states = (float*)d_out;                // scratch; dead before pass3

    const int grid = (nseq / NSEQG) * NCHUNK;     // 44*32 = 1408

    fb_mat_kernel<<<1, 128, 0, stream>>>(a, Mbuf, LCH);
    fb_pass1<<<grid, BLK, 0, stream>>>(x, a, b, states, nfil);
    fb_scan_kernel<<<nfil / 256, 256, 0, stream>>>(states, Mbuf, sinit,
                                                   nfil, NCHUNK);
    fb_pass3<<<grid, BLK, 0, stream>>>(x, a, b, sinit, y, nfil);
}

// Round 6
// 112.400 us; speedup vs baseline: 1.2326x; 1.1034x over previous
//
#include <hip/hip_runtime.h>

// FilterBank: x (128,22,2000) f32, a,b (9,9) f32 -> y (128,22,9,2000) f32
// y[t] = sum_k bn[k] x[t-k] - sum_{k>=1} an[k] y[t-k], zero init state.
//
// R6: exact chunk-scan (pass1 states -> scan(+M folded) -> pass3), tuned for
// occupancy: 9-wave blocks need <=64-72 VGPR to fit 3 blocks/CU (waves/SIMD =
// floor(512/VGPR); 9-wave granularity makes 65+ VGPR collapse to 1 block/CU).
//  - coeffs in SGPRs via readfirstlane (wave==band -> uniform).
//  - LDS 54272 B in pass3 (3 x 54272 = 162816 <= 163840): xs stride 68
//    (slot 17r mod 8 bijective -> conflict-free b128), ys 16-float rows with
//    rotate swizzle p=(j+(r>>1))&3 (conflict-free write + transposed read),
//    x-history overlaid in ys head.
//  - scan: M=A^64 computed in-kernel, per-thread M in regs, 8-deep ring
//    prefetch, fully unrolled (no runtime-indexed reg arrays).

#define TT 2000
#define KK 9
#define NB 9
#define LCH 64
#define NCHUNK 32
#define NSEQG 64
#define BLK 576
#define XP 68
#define PF 8

__device__ __forceinline__ float rfl(float v) {
    return __uint_as_float(__builtin_amdgcn_readfirstlane(__float_as_uint(v)));
}

// ---- 16-step IIR core ----
__device__ __forceinline__ void step16(const float* an, const float* bn,
                                       const float* xc, float* yc,
                                       float* xh, float* yh)
{
#pragma unroll
    for (int i = 0; i < 16; ++i) {
        float s = bn[0] * xc[i];
#pragma unroll
        for (int k = 1; k < KK; ++k) {
            const float xt = (i - k >= 0) ? xc[i - k] : xh[k - i - 1];
            s = fmaf(bn[k], xt, s);
        }
#pragma unroll
        for (int k = 2; k < KK; ++k) {
            const float yt = (i - k >= 0) ? yc[i - k] : yh[k - i - 1];
            s = fmaf(-an[k], yt, s);
        }
        const float y1 = (i >= 1) ? yc[i - 1] : yh[0];
        yc[i] = fmaf(-an[1], y1, s);   // cross-step critical path = 1 FMA
    }
#pragma unroll
    for (int m = 0; m < 8; ++m) { xh[m] = xc[15 - m]; yh[m] = yc[15 - m]; }
}

// cooperative x tile: data rows [seq0,seq0+64) x [t0,t0+64) -> xs (stride XP),
// history x[t0-8,t0) -> hb (stride 8 floats/row). 1152 float4s, 576 thr x 2.
__device__ __forceinline__ void load_xtile(const float* __restrict__ x,
                                           float* xs, float* hb,
                                           int seq0, int t0, int tid)
{
#pragma unroll
    for (int u = 0; u < 2; ++u) {
        const int i4 = tid + u * BLK;
        if (i4 < 1024) {
            const int r  = i4 >> 4, j4 = i4 & 15;
            const int gt = t0 + j4 * 4;
            float4 v = make_float4(0.f, 0.f, 0.f, 0.f);
            if (gt <= TT - 4)
                v = *(const float4*)(x + (size_t)(seq0 + r) * TT + gt);
            *(float4*)(&xs[r * XP + j4 * 4]) = v;
        } else {
            const int h = i4 - 1024;            // 0..127
            const int r = h >> 1, part = h & 1;
            const int gt = t0 - 8 + part * 4;
            float4 v = make_float4(0.f, 0.f, 0.f, 0.f);
            if (gt >= 0)
                v = *(const float4*)(x + (size_t)(seq0 + r) * TT + gt);
            *(float4*)(&hb[r * 8 + part * 4]) = v;
        }
    }
}

__device__ __forceinline__ void load_coeffs_sgpr(const float* a, const float* b,
                                                 int w, float* an, float* bn)
{
    const float inv = rfl(1.0f / a[w * KK]);
#pragma unroll
    for (int k = 0; k < KK; ++k) {
        an[k] = rfl(a[w * KK + k] * inv);
        bn[k] = rfl(b[w * KK + k] * inv);
    }
}

// ---- pass1: chunk from zero y-state (exact x history), emit end state ----
__global__ __launch_bounds__(BLK, 7) void fb_pass1(
    const float* __restrict__ x, const float* __restrict__ a,
    const float* __restrict__ b, float* __restrict__ st, int nfil)
{
    __shared__ float xs[NSEQG * XP];     // 17408 B
    __shared__ float hs[NSEQG * 8];      //  2048 B
    const int tid  = threadIdx.x;
    const int c    = blockIdx.x & (NCHUNK - 1);
    const int g    = blockIdx.x >> 5;
    const int seq0 = g * NSEQG;
    const int t0   = c * LCH;
    const int nit  = (c == NCHUNK - 1) ? ((TT - t0 + 15) >> 4) : (LCH >> 4);

    load_xtile(x, xs, hs, seq0, t0, tid);

    const int w = __builtin_amdgcn_readfirstlane(tid >> 6);   // band
    const int r = tid & 63;

    float an[KK], bn[KK];
    load_coeffs_sgpr(a, b, w, an, bn);

    __syncthreads();

    float xh[8], yh[8] = {0.f,0.f,0.f,0.f,0.f,0.f,0.f,0.f};
    {
        float4 h0 = *(const float4*)(&hs[r * 8]);       // x[t0-8..t0-5]
        float4 h1 = *(const float4*)(&hs[r * 8 + 4]);   // x[t0-4..t0-1]
        xh[0]=h1.w; xh[1]=h1.z; xh[2]=h1.y; xh[3]=h1.x;
        xh[4]=h0.w; xh[5]=h0.z; xh[6]=h0.y; xh[7]=h0.x;
    }

    for (int it = 0; it < nit; ++it) {
        float xc[16], yc[16];
        const float4* xb = (const float4*)(&xs[r * XP + it * 16]);
        float4 v0 = xb[0], v1 = xb[1], v2 = xb[2], v3 = xb[3];
        xc[0]=v0.x; xc[1]=v0.y; xc[2]=v0.z; xc[3]=v0.w;
        xc[4]=v1.x; xc[5]=v1.y; xc[6]=v1.z; xc[7]=v1.w;
        xc[8]=v2.x; xc[9]=v2.y; xc[10]=v2.z; xc[11]=v2.w;
        xc[12]=v3.x; xc[13]=v3.y; xc[14]=v3.z; xc[15]=v3.w;
        step16(an, bn, xc, yc, xh, yh);
    }

    const int fil = (seq0 + r) * NB + w;
    float4* sv = (float4*)(st + ((size_t)c * nfil + fil) * 8);
    sv[0] = make_float4(yh[0], yh[1], yh[2], yh[3]);
    sv[1] = make_float4(yh[4], yh[5], yh[6], yh[7]);
}

// ---- scan (M folded in): sinit[0]=0; sinit[c] = st[c-1] + M*sinit[c-1] ----
__global__ __launch_bounds__(128, 2) void fb_scan(
    const float* __restrict__ states0, const float* __restrict__ a,
    float* __restrict__ sinit, int nfil)
{
    __shared__ float Ms[NB * 64];
    const int tid = threadIdx.x;
    if (tid < NB * 8) {                       // M = A^LCH, column per thread
        const int band = tid >> 3, j = tid & 7;
        float an[KK];
        const float inv = 1.0f / a[band * KK];
#pragma unroll
        for (int k = 0; k < KK; ++k) an[k] = a[band * KK + k] * inv;
        float yh[8] = {0.f,0.f,0.f,0.f,0.f,0.f,0.f,0.f};
        yh[j] = 1.0f;
        for (int t = 0; t < LCH; ++t) {
            float s = 0.f;
#pragma unroll
            for (int k = 1; k < KK; ++k) s = fmaf(-an[k], yh[k - 1], s);
#pragma unroll
            for (int m = 7; m >= 1; --m) yh[m] = yh[m - 1];
            yh[0] = s;
        }
#pragma unroll
        for (int m = 0; m < 8; ++m) Ms[band * 64 + m * 8 + j] = yh[m];
    }
    __syncthreads();

    const int fil  = blockIdx.x * 128 + tid;
    const int band = fil % NB;
    float M[64];
#pragma unroll
    for (int i = 0; i < 64; ++i) M[i] = Ms[band * 64 + i];

    const size_t base = (size_t)fil * 8;
    float4 eA[PF], eB[PF];
#pragma unroll
    for (int p = 0; p < PF; ++p) {
        int cc = (p > NCHUNK - 2) ? (NCHUNK - 2) : p;
        const float4* ep = (const float4*)(states0 + (size_t)cc * nfil * 8 + base);
        eA[p] = ep[0]; eB[p] = ep[1];
    }

    float s[8] = {0.f,0.f,0.f,0.f,0.f,0.f,0.f,0.f};
    {
        float4 z = make_float4(0.f, 0.f, 0.f, 0.f);
        float4* sv = (float4*)(sinit + base);
        sv[0] = z; sv[1] = z;
    }
#pragma unroll
    for (int c = 1; c < NCHUNK; ++c) {
        const int idx = c - 1, pb = idx & (PF - 1);
        const float e[8] = { eA[pb].x, eA[pb].y, eA[pb].z, eA[pb].w,
                             eB[pb].x, eB[pb].y, eB[pb].z, eB[pb].w };
        int nx = idx + PF; if (nx > NCHUNK - 2) nx = NCHUNK - 2;
        const float4* np = (const float4*)(states0 + (size_t)nx * nfil * 8 + base);
        eA[pb] = np[0]; eB[pb] = np[1];

        float ns[8];
#pragma unroll
        for (int m = 0; m < 8; ++m) {
            float acc = e[m];
#pragma unroll
            for (int j = 0; j < 8; ++j) acc = fmaf(M[m * 8 + j], s[j], acc);
            ns[m] = acc;
        }
#pragma unroll
        for (int m = 0; m < 8; ++m) s[m] = ns[m];

        float4* sv = (float4*)(sinit + (size_t)c * nfil * 8 + base);
        sv[0] = make_float4(s[0], s[1], s[2], s[3]);
        sv[1] = make_float4(s[4], s[5], s[6], s[7]);
    }
}

// ---- pass3: chunk from exact init state, write y via swizzled LDS ----
__global__ __launch_bounds__(BLK, 7) void fb_pass3(
    const float* __restrict__ x, const float* __restrict__ a,
    const float* __restrict__ b, const float* __restrict__ sinit,
    float* __restrict__ y, int nfil)
{
    __shared__ float xs[NSEQG * XP];     // 17408 B
    __shared__ float ys[BLK * 16];       // 36864 B; head doubles as x-history
    const int tid  = threadIdx.x;
    const int c    = blockIdx.x & (NCHUNK - 1);
    const int g    = blockIdx.x >> 5;
    const int seq0 = g * NSEQG;
    const int t0   = c * LCH;
    const int nit  = (c == NCHUNK - 1) ? ((TT - t0 + 15) >> 4) : (LCH >> 4);

    load_xtile(x, xs, ys, seq0, t0, tid);   // history -> ys[0:512]

    const int w = __builtin_amdgcn_readfirstlane(tid >> 6);   // band
    const int r = tid & 63;
    const int fil = (seq0 + r) * NB + w;

    float an[KK], bn[KK];
    load_coeffs_sgpr(a, b, w, an, bn);

    float xh[8], yh[8];
    {
        const float4* sv = (const float4*)(sinit + ((size_t)c * nfil + fil) * 8);
        float4 s0 = sv[0], s1 = sv[1];
        yh[0]=s0.x; yh[1]=s0.y; yh[2]=s0.z; yh[3]=s0.w;
        yh[4]=s1.x; yh[5]=s1.y; yh[6]=s1.z; yh[7]=s1.w;
    }

    __syncthreads();                        // xtile + history visible
    {
        float4 h0 = *(const float4*)(&ys[r * 8]);
        float4 h1 = *(const float4*)(&ys[r * 8 + 4]);
        xh[0]=h1.w; xh[1]=h1.z; xh[2]=h1.y; xh[3]=h1.x;
        xh[4]=h0.w; xh[5]=h0.z; xh[6]=h0.y; xh[7]=h0.x;
    }
    __syncthreads();                        // all history reads done before
                                            // ys is reused for staging

    const int q   = r >> 2;                 // 0..15
    const int cc  = r & 3;
    const int rot = (r >> 1) & 3;           // write-side rotate
    const int qh  = (q >> 1) & 3;           // read-side rotate

    for (int it = 0; it < nit; ++it) {
        float xc[16], yc[16];
        const float4* xb = (const float4*)(&xs[r * XP + it * 16]);
        float4 v0 = xb[0], v1 = xb[1], v2 = xb[2], v3 = xb[3];
        xc[0]=v0.x; xc[1]=v0.y; xc[2]=v0.z; xc[3]=v0.w;
        xc[4]=v1.x; xc[5]=v1.y; xc[6]=v1.z; xc[7]=v1.w;
        xc[8]=v2.x; xc[9]=v2.y; xc[10]=v2.z; xc[11]=v2.w;
        xc[12]=v3.x; xc[13]=v3.y; xc[14]=v3.z; xc[15]=v3.w;
        step16(an, bn, xc, yc, xh, yh);

        // stage own row, rotate-swizzled (wave-private region)
        float4* yl = (float4*)(&ys[(w * 64 + r) * 16]);
        yl[(0 + rot) & 3] = make_float4(yc[0],  yc[1],  yc[2],  yc[3]);
        yl[(1 + rot) & 3] = make_float4(yc[4],  yc[5],  yc[6],  yc[7]);
        yl[(2 + rot) & 3] = make_float4(yc[8],  yc[9],  yc[10], yc[11]);
        yl[(3 + rot) & 3] = make_float4(yc[12], yc[13], yc[14], yc[15]);
        asm volatile("s_waitcnt lgkmcnt(0)" ::: "memory");

        // transposed store: 4 lanes per filter -> full 64B lines
#pragma unroll
        for (int s2 = 0; s2 < 4; ++s2) {
            const int row = s2 * 16 + q;
            const int p   = (cc + qh) & 3;
            float4 v = *(const float4*)(&ys[(w * 64 + row) * 16 + p * 4]);
            float* dst = y + ((size_t)(seq0 + row) * NB + w) * TT
                           + t0 + it * 16 + cc * 4;
            *(float4*)dst = v;
        }
    }
}

// ---- fallback: exact thread-per-filter, full length ----
__global__ __launch_bounds__(64) void fb_fallback(
    const float* __restrict__ x, const float* __restrict__ a,
    const float* __restrict__ b, float* __restrict__ y, int nfil)
{
    const int tid = blockIdx.x * 64 + threadIdx.x;
    if (tid >= nfil) return;
    const int seq  = tid / NB;
    const int band = tid - seq * NB;

    const float* xp = x + (size_t)seq * TT;
    float*       yp = y + (size_t)tid * TT;

    float an[KK], bn[KK];
    const float inv = 1.0f / a[band * KK];
#pragma unroll
    for (int k = 0; k < KK; ++k) {
        an[k] = a[band * KK + k] * inv;
        bn[k] = b[band * KK + k] * inv;
    }

    float xh[8] = {0.f,0.f,0.f,0.f,0.f,0.f,0.f,0.f};
    float yh[8] = {0.f,0.f,0.f,0.f,0.f,0.f,0.f,0.f};

    for (int t0 = 0; t0 < TT; t0 += 16) {
        float xc[16], yc[16];
        const float4* xv = (const float4*)(xp + t0);
        float4 v0 = xv[0], v1 = xv[1], v2 = xv[2], v3 = xv[3];
        xc[0]=v0.x; xc[1]=v0.y; xc[2]=v0.z; xc[3]=v0.w;
        xc[4]=v1.x; xc[5]=v1.y; xc[6]=v1.z; xc[7]=v1.w;
        xc[8]=v2.x; xc[9]=v2.y; xc[10]=v2.z; xc[11]=v2.w;
        xc[12]=v3.x; xc[13]=v3.y; xc[14]=v3.z; xc[15]=v3.w;
        step16(an, bn, xc, yc, xh, yh);
        float4* yv = (float4*)(yp + t0);
        yv[0] = make_float4(yc[0],  yc[1],  yc[2],  yc[3]);
        yv[1] = make_float4(yc[4],  yc[5],  yc[6],  yc[7]);
        yv[2] = make_float4(yc[8],  yc[9],  yc[10], yc[11]);
        yv[3] = make_float4(yc[12], yc[13], yc[14], yc[15]);
    }
}

extern "C" void kernel_launch(void* const* d_in, const int* in_sizes, int n_in,
                              void* d_out, int out_size, void* d_ws, size_t ws_size,
                              hipStream_t stream) {
    const float* x = (const float*)d_in[0];
    const float* a = (const float*)d_in[1];
    const float* b = (const float*)d_in[2];
    float*       y = (float*)d_out;

    const int nseq = in_sizes[0] / TT;      // 2816
    const int nfil = nseq * NB;             // 25344

    const size_t need = (size_t)NCHUNK * nfil * 8 * 4;   // ~26 MB
    if ((nseq % NSEQG) != 0 || (nfil % 128) != 0 || need > ws_size) {
        fb_fallback<<<(nfil + 63) / 64, 64, 0, stream>>>(x, a, b, y, nfil);
        return;
    }

    float* sinit  = (float*)d_ws;           // NCHUNK*nfil*8 floats
    float* states = (float*)d_out;          // scratch; dead before pass3

    const int grid = (nseq / NSEQG) * NCHUNK;     // 44*32 = 1408

    fb_pass1<<<grid, BLK, 0, stream>>>(x, a, b, states, nfil);
    fb_scan<<<nfil / 128, 128, 0, stream>>>(states, a, sinit, nfil);
    fb_pass3<<<grid, BLK, 0, stream>>>(x, a, b, sinit, y, nfil);
}

// Round 8
// 103.571 us; speedup vs baseline: 1.3377x; 1.0852x over previous
//
#include <hip/hip_runtime.h>

// FilterBank: x (128,22,2000) f32, a,b (9,9) f32 -> y (128,22,9,2000) f32
// y[t] = sum_k bn[k] x[t-k] - sum_{k>=1} an[k] y[t-k], zero init state.
//
// R7 (resubmit; previous round died on infra): exact chunk-scan,
// LCH=128 / NCHUNK=16 (was 64/32):
//  - per-wave inner iterations 4 -> 8: halves per-chunk fixed overhead
//    (tile load, barriers, hist+sinit+coeff setup) relative to compute.
//  - scan: 15 sequential matvecs (was 31), sinit+states traffic halves.
//  - pass1: full 136-float row tile, stride 140 (35r mod 8 bijective ->
//    conflict-free b128). 35.8 KB LDS.
//  - pass3: xs sub-tiled 2x64 (17.4 KB, reloaded mid-chunk) + ys 36.9 KB
//    transposed-store staging = 54.3 KB -> 3 blocks/CU (27 waves).
//  - x is read exactly once per pass (chunks partition T) - no warm-up dup.

#define TT 2000
#define KK 9
#define NB 9
#define LCH 128
#define NCHUNK 16
#define BLK 576
#define XP1 140        // pass1 row stride (8 hist + 128 data + pad)
#define XP3 68         // pass3 sub-tile row stride (64 data + pad)
#define PF 8

__device__ __forceinline__ float rfl(float v) {
    return __uint_as_float(__builtin_amdgcn_readfirstlane(__float_as_uint(v)));
}

// ---- 16-step IIR core ----
__device__ __forceinline__ void step16(const float* an, const float* bn,
                                       const float* xc, float* yc,
                                       float* xh, float* yh)
{
#pragma unroll
    for (int i = 0; i < 16; ++i) {
        float s = bn[0] * xc[i];
#pragma unroll
        for (int k = 1; k < KK; ++k) {
            const float xt = (i - k >= 0) ? xc[i - k] : xh[k - i - 1];
            s = fmaf(bn[k], xt, s);
        }
#pragma unroll
        for (int k = 2; k < KK; ++k) {
            const float yt = (i - k >= 0) ? yc[i - k] : yh[k - i - 1];
            s = fmaf(-an[k], yt, s);
        }
        const float y1 = (i >= 1) ? yc[i - 1] : yh[0];
        yc[i] = fmaf(-an[1], y1, s);   // cross-step critical path = 1 FMA
    }
#pragma unroll
    for (int m = 0; m < 8; ++m) { xh[m] = xc[15 - m]; yh[m] = yc[15 - m]; }
}

__device__ __forceinline__ void load_coeffs_sgpr(const float* a, const float* b,
                                                 int w, float* an, float* bn)
{
    const float inv = rfl(1.0f / a[w * KK]);
#pragma unroll
    for (int k = 0; k < KK; ++k) {
        an[k] = rfl(a[w * KK + k] * inv);
        bn[k] = rfl(b[w * KK + k] * inv);
    }
}

__device__ __forceinline__ void unpack16(const float4* xb, float* xc)
{
    float4 v0 = xb[0], v1 = xb[1], v2 = xb[2], v3 = xb[3];
    xc[0]=v0.x; xc[1]=v0.y; xc[2]=v0.z; xc[3]=v0.w;
    xc[4]=v1.x; xc[5]=v1.y; xc[6]=v1.z; xc[7]=v1.w;
    xc[8]=v2.x; xc[9]=v2.y; xc[10]=v2.z; xc[11]=v2.w;
    xc[12]=v3.x; xc[13]=v3.y; xc[14]=v3.z; xc[15]=v3.w;
}

// ---- pass1: chunk from zero y-state (exact x history), emit end state ----
__global__ __launch_bounds__(BLK, 7) void fb_pass1(
    const float* __restrict__ x, const float* __restrict__ a,
    const float* __restrict__ b, float* __restrict__ st, int nfil)
{
    __shared__ float xs[64 * XP1];       // 35840 B
    const int tid  = threadIdx.x;
    const int c    = blockIdx.x & (NCHUNK - 1);
    const int g    = blockIdx.x >> 4;
    const int seq0 = g * 64;
    const int t0   = c * LCH;
    const int t_end = (t0 + LCH < TT) ? t0 + LCH : TT;
    const int nit  = (t_end - t0) >> 4;             // 8 or 5

    // full row tile [t0-8, t0+128): 64 rows x 34 float4
#pragma unroll
    for (int u = 0; u < 4; ++u) {
        const int i4 = tid + u * BLK;
        if (i4 < 2176) {
            const int r  = i4 / 34;
            const int j4 = i4 - r * 34;
            const int gt = t0 - 8 + j4 * 4;
            float4 v = make_float4(0.f, 0.f, 0.f, 0.f);
            if (gt >= 0 && gt <= TT - 4)
                v = *(const float4*)(x + (size_t)(seq0 + r) * TT + gt);
            *(float4*)(&xs[r * XP1 + j4 * 4]) = v;
        }
    }

    const int w = __builtin_amdgcn_readfirstlane(tid >> 6);   // band
    const int r = tid & 63;

    float an[KK], bn[KK];
    load_coeffs_sgpr(a, b, w, an, bn);

    __syncthreads();

    float xh[8], yh[8] = {0.f,0.f,0.f,0.f,0.f,0.f,0.f,0.f};
    {
        float4 h0 = *(const float4*)(&xs[r * XP1]);       // x[t0-8..t0-5]
        float4 h1 = *(const float4*)(&xs[r * XP1 + 4]);   // x[t0-4..t0-1]
        xh[0]=h1.w; xh[1]=h1.z; xh[2]=h1.y; xh[3]=h1.x;
        xh[4]=h0.w; xh[5]=h0.z; xh[6]=h0.y; xh[7]=h0.x;
    }

    for (int it = 0; it < nit; ++it) {
        float xc[16], yc[16];
        unpack16((const float4*)(&xs[r * XP1 + 8 + it * 16]), xc);
        step16(an, bn, xc, yc, xh, yh);
    }

    const int fil = (seq0 + r) * NB + w;
    float4* sv = (float4*)(st + ((size_t)c * nfil + fil) * 8);
    sv[0] = make_float4(yh[0], yh[1], yh[2], yh[3]);
    sv[1] = make_float4(yh[4], yh[5], yh[6], yh[7]);
}

// ---- scan (M=A^LCH folded in): sinit[c] = st[c-1] + M*sinit[c-1] ----
__global__ __launch_bounds__(256, 2) void fb_scan(
    const float* __restrict__ states0, const float* __restrict__ a,
    float* __restrict__ sinit, int nfil)
{
    __shared__ float Ms[NB * 64];
    const int tid = threadIdx.x;
    if (tid < NB * 8) {                       // M = A^LCH, column per thread
        const int band = tid >> 3, j = tid & 7;
        float an[KK];
        const float inv = 1.0f / a[band * KK];
#pragma unroll
        for (int k = 0; k < KK; ++k) an[k] = a[band * KK + k] * inv;
        float yh[8] = {0.f,0.f,0.f,0.f,0.f,0.f,0.f,0.f};
        yh[j] = 1.0f;
        for (int t = 0; t < LCH; ++t) {
            float s = 0.f;
#pragma unroll
            for (int k = 1; k < KK; ++k) s = fmaf(-an[k], yh[k - 1], s);
#pragma unroll
            for (int m = 7; m >= 1; --m) yh[m] = yh[m - 1];
            yh[0] = s;
        }
#pragma unroll
        for (int m = 0; m < 8; ++m) Ms[band * 64 + m * 8 + j] = yh[m];
    }
    __syncthreads();

    const int fil  = blockIdx.x * 256 + tid;
    const int band = fil % NB;
    float M[64];
#pragma unroll
    for (int i = 0; i < 64; ++i) M[i] = Ms[band * 64 + i];

    const size_t base = (size_t)fil * 8;
    float4 eA[PF], eB[PF];
#pragma unroll
    for (int p = 0; p < PF; ++p) {
        int cc = (p > NCHUNK - 2) ? (NCHUNK - 2) : p;
        const float4* ep = (const float4*)(states0 + (size_t)cc * nfil * 8 + base);
        eA[p] = ep[0]; eB[p] = ep[1];
    }

    float s[8] = {0.f,0.f,0.f,0.f,0.f,0.f,0.f,0.f};
    {
        float4 z = make_float4(0.f, 0.f, 0.f, 0.f);
        float4* sv = (float4*)(sinit + base);
        sv[0] = z; sv[1] = z;
    }
#pragma unroll
    for (int c = 1; c < NCHUNK; ++c) {
        const int idx = c - 1, pb = idx & (PF - 1);
        const float e[8] = { eA[pb].x, eA[pb].y, eA[pb].z, eA[pb].w,
                             eB[pb].x, eB[pb].y, eB[pb].z, eB[pb].w };
        int nx = idx + PF; if (nx > NCHUNK - 2) nx = NCHUNK - 2;
        const float4* np = (const float4*)(states0 + (size_t)nx * nfil * 8 + base);
        eA[pb] = np[0]; eB[pb] = np[1];

        float ns[8];
#pragma unroll
        for (int m = 0; m < 8; ++m) {
            float acc = e[m];
#pragma unroll
            for (int j = 0; j < 8; ++j) acc = fmaf(M[m * 8 + j], s[j], acc);
            ns[m] = acc;
        }
#pragma unroll
        for (int m = 0; m < 8; ++m) s[m] = ns[m];

        float4* sv = (float4*)(sinit + (size_t)c * nfil * 8 + base);
        sv[0] = make_float4(s[0], s[1], s[2], s[3]);
        sv[1] = make_float4(s[4], s[5], s[6], s[7]);
    }
}

// ---- pass3: chunk from exact init state, write y via swizzled LDS ----
__global__ __launch_bounds__(BLK, 7) void fb_pass3(
    const float* __restrict__ x, const float* __restrict__ a,
    const float* __restrict__ b, const float* __restrict__ sinit,
    float* __restrict__ y, int nfil)
{
    __shared__ float xs[64 * XP3];       // 17408 B (one 64-step sub-tile)
    __shared__ float ys[BLK * 16];       // 36864 B; head doubles as x-history
    const int tid  = threadIdx.x;
    const int c    = blockIdx.x & (NCHUNK - 1);
    const int g    = blockIdx.x >> 4;
    const int seq0 = g * 64;
    const int t0   = c * LCH;
    const int t_end = (t0 + LCH < TT) ? t0 + LCH : TT;
    const int nit  = (t_end - t0) >> 4;             // 8 or 5
    const int nsub = (nit + 3) >> 2;                // 2

    // history x[t0-8..t0-1] -> ys[0:512]
    if (tid < 128) {
        const int hr = tid >> 1, part = tid & 1;
        const int gt = t0 - 8 + part * 4;
        float4 v = make_float4(0.f, 0.f, 0.f, 0.f);
        if (gt >= 0)
            v = *(const float4*)(x + (size_t)(seq0 + hr) * TT + gt);
        *(float4*)(&ys[hr * 8 + part * 4]) = v;
    }
    // sub-tile 0: [t0, t0+64)
#pragma unroll
    for (int u = 0; u < 2; ++u) {
        const int i4 = tid + u * BLK;
        if (i4 < 1024) {
            const int rr = i4 >> 4, j4 = i4 & 15;
            const int gt = t0 + j4 * 4;
            float4 v = make_float4(0.f, 0.f, 0.f, 0.f);
            if (gt <= TT - 4)
                v = *(const float4*)(x + (size_t)(seq0 + rr) * TT + gt);
            *(float4*)(&xs[rr * XP3 + j4 * 4]) = v;
        }
    }

    const int w = __builtin_amdgcn_readfirstlane(tid >> 6);   // band
    const int r = tid & 63;
    const int fil = (seq0 + r) * NB + w;

    float an[KK], bn[KK];
    load_coeffs_sgpr(a, b, w, an, bn);

    float xh[8], yh[8];
    {
        const float4* sv = (const float4*)(sinit + ((size_t)c * nfil + fil) * 8);
        float4 s0 = sv[0], s1 = sv[1];
        yh[0]=s0.x; yh[1]=s0.y; yh[2]=s0.z; yh[3]=s0.w;
        yh[4]=s1.x; yh[5]=s1.y; yh[6]=s1.z; yh[7]=s1.w;
    }

    __syncthreads();                        // tile + history visible
    {
        float4 h0 = *(const float4*)(&ys[r * 8]);
        float4 h1 = *(const float4*)(&ys[r * 8 + 4]);
        xh[0]=h1.w; xh[1]=h1.z; xh[2]=h1.y; xh[3]=h1.x;
        xh[4]=h0.w; xh[5]=h0.z; xh[6]=h0.y; xh[7]=h0.x;
    }
    __syncthreads();                        // history consumed; ys reusable

    const int q   = r >> 2;                 // 0..15
    const int cc  = r & 3;
    const int rot = (r >> 1) & 3;           // write-side rotate
    const int qh  = (q >> 1) & 3;           // read-side rotate

    int itg = 0;
    for (int s2 = 0; s2 < nsub; ++s2) {
        if (s2) {
            __syncthreads();                // all waves done reading xs
            const int ts = t0 + s2 * 64;
#pragma unroll
            for (int u = 0; u < 2; ++u) {
                const int i4 = tid + u * BLK;
                if (i4 < 1024) {
                    const int rr = i4 >> 4, j4 = i4 & 15;
                    const int gt = ts + j4 * 4;
                    float4 v = make_float4(0.f, 0.f, 0.f, 0.f);
                    if (gt <= TT - 4)
                        v = *(const float4*)(x + (size_t)(seq0 + rr) * TT + gt);
                    *(float4*)(&xs[rr * XP3 + j4 * 4]) = v;
                }
            }
            __syncthreads();                // sub-tile ready
        }
        const int ni = (nit - s2 * 4 < 4) ? nit - s2 * 4 : 4;
        for (int il = 0; il < ni; ++il, ++itg) {
            float xc[16], yc[16];
            unpack16((const float4*)(&xs[r * XP3 + il * 16]), xc);
            step16(an, bn, xc, yc, xh, yh);

            // stage own row, rotate-swizzled (wave-private region)
            float4* yl = (float4*)(&ys[(w * 64 + r) * 16]);
            yl[(0 + rot) & 3] = make_float4(yc[0],  yc[1],  yc[2],  yc[3]);
            yl[(1 + rot) & 3] = make_float4(yc[4],  yc[5],  yc[6],  yc[7]);
            yl[(2 + rot) & 3] = make_float4(yc[8],  yc[9],  yc[10], yc[11]);
            yl[(3 + rot) & 3] = make_float4(yc[12], yc[13], yc[14], yc[15]);
            asm volatile("s_waitcnt lgkmcnt(0)" ::: "memory");

            // transposed store: 4 lanes per filter -> full 64B lines
#pragma unroll
            for (int s3 = 0; s3 < 4; ++s3) {
                const int row = s3 * 16 + q;
                const int p   = (cc + qh) & 3;
                float4 v = *(const float4*)(&ys[(w * 64 + row) * 16 + p * 4]);
                float* dst = y + ((size_t)(seq0 + row) * NB + w) * TT
                               + t0 + itg * 16 + cc * 4;
                *(float4*)dst = v;
            }
        }
    }
}

// ---- fallback: exact thread-per-filter, full length ----
__global__ __launch_bounds__(64) void fb_fallback(
    const float* __restrict__ x, const float* __restrict__ a,
    const float* __restrict__ b, float* __restrict__ y, int nfil)
{
    const int tid = blockIdx.x * 64 + threadIdx.x;
    if (tid >= nfil) return;
    const int seq  = tid / NB;
    const int band = tid - seq * NB;

    const float* xp = x + (size_t)seq * TT;
    float*       yp = y + (size_t)tid * TT;

    float an[KK], bn[KK];
    const float inv = 1.0f / a[band * KK];
#pragma unroll
    for (int k = 0; k < KK; ++k) {
        an[k] = a[band * KK + k] * inv;
        bn[k] = b[band * KK + k] * inv;
    }

    float xh[8] = {0.f,0.f,0.f,0.f,0.f,0.f,0.f,0.f};
    float yh[8] = {0.f,0.f,0.f,0.f,0.f,0.f,0.f,0.f};

    for (int t0 = 0; t0 < TT; t0 += 16) {
        float xc[16], yc[16];
        unpack16((const float4*)(xp + t0), xc);
        step16(an, bn, xc, yc, xh, yh);
        float4* yv = (float4*)(yp + t0);
        yv[0] = make_float4(yc[0],  yc[1],  yc[2],  yc[3]);
        yv[1] = make_float4(yc[4],  yc[5],  yc[6],  yc[7]);
        yv[2] = make_float4(yc[8],  yc[9],  yc[10], yc[11]);
        yv[3] = make_float4(yc[12], yc[13], yc[14], yc[15]);
    }
}

extern "C" void kernel_launch(void* const* d_in, const int* in_sizes, int n_in,
                              void* d_out, int out_size, void* d_ws, size_t ws_size,
                              hipStream_t stream) {
    const float* x = (const float*)d_in[0];
    const float* a = (const float*)d_in[1];
    const float* b = (const float*)d_in[2];
    float*       y = (float*)d_out;

    const int nseq = in_sizes[0] / TT;      // 2816
    const int nfil = nseq * NB;             // 25344

    const size_t need = (size_t)NCHUNK * nfil * 8 * 4;   // ~13 MB
    if ((nseq % 64) != 0 || (nfil % 256) != 0 || need > ws_size) {
        fb_fallback<<<(nfil + 63) / 64, 64, 0, stream>>>(x, a, b, y, nfil);
        return;
    }

    float* sinit  = (float*)d_ws;           // NCHUNK*nfil*8 floats
    float* states = (float*)d_out;          // scratch; dead before pass3

    const int grid = (nseq / 64) * NCHUNK;  // 44*16 = 704

    fb_pass1<<<grid, BLK, 0, stream>>>(x, a, b, states, nfil);
    fb_scan<<<nfil / 256, 256, 0, stream>>>(states, a, sinit, nfil);
    fb_pass3<<<grid, BLK, 0, stream>>>(x, a, b, sinit, y, nfil);
}